// Round 5
// baseline (34.136 us; speedup 1.0000x reference)
//
#include <hip/hip_runtime.h>

// conv_transpose3d(x, identity weights, K=3, stride=1, pad=1) == gather:
//   out[b,z,y,w] = sum over (kz,ky,kx) of x[b, kz*9+ky*3+kx, z+1-kz, y+1-ky, w+1-kx]
// with out-of-range spatial taps contributing 0.
// Input  x:  (2, 27, 96, 96, 96) f32, ~191 MB (read exactly once)
// Output out:(2,  1, 96, 96, 96) f32, ~7 MB
// HBM-bound: floor ~198 MB / 6.3 TB/s ~= 31.5 us.
// This version: 8 outputs per thread (two float4 loads per channel-row),
// halving edge-scalar loads and per-thread index math per output byte.

#define DIM 96
#define KK 3
#define NC 27

__global__ __launch_bounds__(256) void fold_gather8_kernel(
    const float* __restrict__ x, float* __restrict__ out) {
  const int nW = DIM / 8;  // 12 octets per row
  int tid = blockIdx.x * blockDim.x + threadIdx.x;

  int wq = tid % nW;
  int t  = tid / nW;
  int y  = t % DIM;
  t     /= DIM;
  int z  = t % DIM;
  int b  = t / DIM;
  int w0 = wq * 8;

  const size_t plane = (size_t)DIM * DIM * DIM;  // 884736
  const float* xb = x + (size_t)b * NC * plane;

  float a0 = 0.f, a1 = 0.f, a2 = 0.f, a3 = 0.f;
  float a4 = 0.f, a5 = 0.f, a6 = 0.f, a7 = 0.f;

  const bool has_left  = (w0 > 0);
  const bool has_right = (w0 + 8 < DIM);

#pragma unroll
  for (int kz = 0; kz < KK; ++kz) {
    int zz = z + 1 - kz;
    if ((unsigned)zz >= (unsigned)DIM) continue;
#pragma unroll
    for (int ky = 0; ky < KK; ++ky) {
      int yy = y + 1 - ky;
      if ((unsigned)yy >= (unsigned)DIM) continue;

      int c0 = (kz * KK + ky) * KK;  // kx = 0,1,2 -> dx = +1, 0, -1
      const float* r_p = xb + (size_t)c0 * plane + (size_t)(zz * DIM + yy) * DIM;
      const float* r_0 = r_p + plane;
      const float* r_m = r_0 + plane;

      // w0 % 8 == 0 and all row bases are multiples of 4 floats -> 16B-aligned.
      float4 p0 = *(const float4*)(r_p + w0);
      float4 p1 = *(const float4*)(r_p + w0 + 4);
      float4 z0 = *(const float4*)(r_0 + w0);
      float4 z1 = *(const float4*)(r_0 + w0 + 4);
      float4 m0 = *(const float4*)(r_m + w0);
      float4 m1 = *(const float4*)(r_m + w0 + 4);
      float left  = has_left  ? r_m[w0 - 1] : 0.f;  // out w0   needs r_m[w0-1]
      float right = has_right ? r_p[w0 + 8] : 0.f;  // out w0+7 needs r_p[w0+8]

      // dx = 0: out[w] += r_0[w]
      a0 += z0.x; a1 += z0.y; a2 += z0.z; a3 += z0.w;
      a4 += z1.x; a5 += z1.y; a6 += z1.z; a7 += z1.w;
      // dx = +1: out[w] += r_p[w+1]
      a0 += p0.y; a1 += p0.z; a2 += p0.w; a3 += p1.x;
      a4 += p1.y; a5 += p1.z; a6 += p1.w; a7 += right;
      // dx = -1: out[w] += r_m[w-1]
      a0 += left; a1 += m0.x; a2 += m0.y; a3 += m0.z;
      a4 += m0.w; a5 += m1.x; a6 += m1.y; a7 += m1.z;
    }
  }

  float* o = out + (size_t)((b * DIM + z) * DIM + y) * DIM + w0;
  *(float4*)(o)     = make_float4(a0, a1, a2, a3);
  *(float4*)(o + 4) = make_float4(a4, a5, a6, a7);
}

extern "C" void kernel_launch(void* const* d_in, const int* in_sizes, int n_in,
                              void* d_out, int out_size, void* d_ws, size_t ws_size,
                              hipStream_t stream) {
  (void)in_sizes; (void)n_in; (void)d_ws; (void)ws_size; (void)out_size;
  const float* x = (const float*)d_in[0];
  float* out = (float*)d_out;

  // total threads: B * D * D * (D/8) = 2 * 96 * 96 * 12 = 221184 (exact multiple of 256)
  const int total_threads = 2 * DIM * DIM * (DIM / 8);
  const int block = 256;
  const int grid = total_threads / block;  // 864
  fold_gather8_kernel<<<grid, block, 0, stream>>>(x, out);
}